// Round 9
// baseline (140.591 us; speedup 1.0000x reference)
//
#include <hip/hip_runtime.h>
#include <math.h>

// DifferentiableLassoSelector: B=65536, n=256, h=32.
// p = 6553.6 - Z^T y > 0 elementwise (~40 sigma margin) => projected-gradient
// QP stays at lam=0 exactly => y_hat = 0 exactly.
// Chebyshev-moment factorization: tanh(W1*x+b1) ~ sum_k c_k T_k(x/X), X=6.5,
// deg 20; Z^T y needs only moments S_i[n] = sum_b y_b T_{i+1}(x[b,n]/X).
// r7/r8 post-mortem: VGPR_Count (40/36) << live accumulators (56/28+) with no
// scratch traffic => compiler parks accumulators in AGPRs (unified file) with
// accvgpr round-trips per accumulate -> VALUBusy 24-28%, 5-9x issue floor.
// Fix: 20 named accumulators (+pipeline ~45 live floats) to stay under the
// parking threshold; deg-20 tail certified on device (fallback if it fails).
// Zero path taken only if min_n(p~ - cert) >= 0 AND max|x| <= X; exact
// exp2-tanh fallback pipeline is flag-guarded.

#define NF 256
#define HID 32
#define BATCHN 65536
#define ALPHA_BF 6553.6f               // ALPHA * BATCH
#define JITTERF 1e-4f
#define QP_ITERS_N 500
#define K2C 2.8853900817779268f        // 2*log2(e): exp2(K2C*u) = e^{2u}
#define XFIX 6.5f
#define INVX (1.0f / 6.5f)
#define DDEG 20                        // Chebyshev degree (c_0..c_20 used)
#define PROW (NF * DDEG)               // 5120 floats per pmom row

// ws float layout:
// 0: flagA | 1: Xobs(uint bits) | 8..72: ypart[64] | 72..136: yabspart[64]
// 7424: ptil[256] | 7680: cert[256]
// 8192:   cws[21][8192]   -> 180224 (region reserved to 245760)
// 245760: tailbuf[8192]   -> 253952 (atomicAdd |c_k| tails, k=21..43)
// 253952: pmom[NC][5120]  OVERLAID WITH fallback buffers (disjoint lifetime)
#define PMOM_OFF 253952

#if __has_builtin(__builtin_amdgcn_exp2f)
__device__ __forceinline__ float fexp2(float x) { return __builtin_amdgcn_exp2f(x); }
#else
__device__ __forceinline__ float fexp2(float x) { return exp2f(x); }
#endif
#if __has_builtin(__builtin_amdgcn_rcpf)
__device__ __forceinline__ float frcp(float x) { return __builtin_amdgcn_rcpf(x); }
#else
__device__ __forceinline__ float frcp(float x) { return 1.0f / x; }
#endif

// ---------------- ysum: y partials + header/tailbuf zero ---------------------
__global__ __launch_bounds__(256) void ysum_kernel(const float* __restrict__ y,
                                                   float* __restrict__ wsf)
{
  const int t = threadIdx.x;
  const int gi = blockIdx.x * 256 + t;        // [0, 16384)
  if (gi == 0) wsf[1] = 0.f;                  // Xobs (atomicMax target)
  if (gi < 8192) wsf[245760 + gi] = 0.f;      // tailbuf
  const int i = gi * 4;
  float4 v = *reinterpret_cast<const float4*>(y + i);
  float s  = (v.x + v.y) + (v.z + v.w);
  float sa = (fabsf(v.x) + fabsf(v.y)) + (fabsf(v.z) + fabsf(v.w));
  #pragma unroll
  for (int m = 1; m < 64; m <<= 1) {
    s  += __shfl_xor(s, m);
    sa += __shfl_xor(sa, m);
  }
  __shared__ float ls[4], la[4];
  int w = t >> 6;
  if ((t & 63) == 0) { ls[w] = s; la[w] = sa; }
  __syncthreads();
  if (t == 0) {
    wsf[8  + blockIdx.x] = (ls[0] + ls[1]) + (ls[2] + ls[3]);
    wsf[72 + blockIdx.x] = (la[0] + la[1]) + (la[2] + la[3]);
  }
}

// ---------------- moment + coefficient kernel --------------------------------
// One Chebyshev step: T_new = 2*xh*T_cur - T_prev; accumulate y*T_new into SK.
#define MSTEP(SK) { \
  float n0 = fmaf(d0, c0, -m0), n1 = fmaf(d1, c1, -m1); \
  m0 = c0; c0 = n0; m1 = c1; c1 = n1; \
  SK = fmaf(yv0, n0, SK); SK = fmaf(yv1, n1, SK); }

#define MGROUP(XA0, XA1, YA) { \
  float yv0 = (YA).x, yv1 = (YA).y; \
  mx = fmaxf(mx, fmaxf(fabsf(XA0), fabsf(XA1))); \
  float h0 = (XA0) * INVX, h1 = (XA1) * INVX; \
  float d0 = h0 + h0, d1 = h1 + h1; \
  float m0 = 1.f, m1 = 1.f, c0 = h0, c1 = h1; \
  s00 = fmaf(yv0, h0, s00); s00 = fmaf(yv1, h1, s00); \
  MSTEP(s01) MSTEP(s02) MSTEP(s03) MSTEP(s04) MSTEP(s05) MSTEP(s06) \
  MSTEP(s07) MSTEP(s08) MSTEP(s09) MSTEP(s10) MSTEP(s11) MSTEP(s12) \
  MSTEP(s13) MSTEP(s14) MSTEP(s15) MSTEP(s16) MSTEP(s17) MSTEP(s18) \
  MSTEP(s19) }

__global__ __launch_bounds__(256, 4) void momentcoeff_kernel(
    const float* __restrict__ x, const float* __restrict__ y,
    const float* __restrict__ W1, const float* __restrict__ b1,
    float* __restrict__ wsf, int NC)
{
  const int t = threadIdx.x;
  if ((int)blockIdx.x < NC) {
    // ---- moment path: thread = feature n; block = row chunk ----
    const int n = t;
    const int rows = BATCHN / NC;              // >= 32
    const int b0 = blockIdx.x * rows;
    const float* xp = x + (size_t)b0 * NF + n;
    const float2* yp2 = reinterpret_cast<const float2*>(y + b0);
    float s00=0.f,s01=0.f,s02=0.f,s03=0.f,s04=0.f,s05=0.f,s06=0.f,
          s07=0.f,s08=0.f,s09=0.f,s10=0.f,s11=0.f,s12=0.f,s13=0.f,
          s14=0.f,s15=0.f,s16=0.f,s17=0.f,s18=0.f,s19=0.f;
    float mx = 0.f;
    // 2-row groups, prefetch depth 2
    const int G = rows >> 1;                   // >= 16
    float xa0 = xp[0],          xa1 = xp[NF];
    float2 ya = yp2[0];
    float xb0 = xp[2 * NF],     xb1 = xp[3 * NF];
    float2 yb = yp2[1];
    const float* xq = xp + 4 * NF;
    for (int g = 0; g < G - 2; ++g) {
      float xn0 = xq[0], xn1 = xq[NF];
      float2 yn = yp2[g + 2];
      MGROUP(xa0, xa1, ya);
      xa0 = xb0; xa1 = xb1; ya = yb;
      xb0 = xn0; xb1 = xn1; yb = yn;
      xq += 2 * NF;
    }
    MGROUP(xa0, xa1, ya);
    MGROUP(xb0, xb1, yb);
    // |x| max: wave-reduce + order-exact atomicMax on bits
    #pragma unroll
    for (int m = 1; m < 64; m <<= 1) mx = fmaxf(mx, __shfl_xor(mx, m));
    if ((t & 63) == 0)
      atomicMax(reinterpret_cast<unsigned int*>(&wsf[1]), __float_as_uint(mx));
    // 20 floats per n = 80B, 16B-aligned (5 x float4)
    float4* dst = reinterpret_cast<float4*>(
        wsf + PMOM_OFF + (size_t)blockIdx.x * PROW + n * DDEG);
    dst[0] = make_float4(s00, s01, s02, s03);
    dst[1] = make_float4(s04, s05, s06, s07);
    dst[2] = make_float4(s08, s09, s10, s11);
    dst[3] = make_float4(s12, s13, s14, s15);
    dst[4] = make_float4(s16, s17, s18, s19);
  } else {
    // ---- coeff path: thread = (id, k); c_k[id] = (2/44) sum_j f_j cos(k th_j)
    const int cb = blockIdx.x - NC;            // [0, 1408)
    const int k  = cb >> 5;                    // 0..43
    const int id = (cb & 31) * 256 + t;        // 0..8191 = n*32+h
    const float aX = W1[id] * XFIX;
    const float bb = b1[id];
    const float kf = (float)k;
    const float C1 = (float)(M_PI / 44.0);
    float acc = 0.f;
    #pragma unroll 4
    for (int jn = 0; jn < 44; ++jn) {
      float ang = ((float)jn + 0.5f) * C1;
      float tj  = __cosf(ang);
      float u   = fmaf(aX, tj, bb);
      float f   = fmaf(-2.f, frcp(fexp2(K2C * u) + 1.f), 1.f);  // exact tanh
      acc = fmaf(f, __cosf(kf * ang), acc);
    }
    const float sc = 2.0f / 44.0f;
    if (k == 0)         wsf[8192 + id] = acc * (1.0f / 44.0f);
    else if (k <= DDEG) wsf[8192 + k * 8192 + id] = acc * sc;
    else                atomicAdd(&wsf[245760 + id], fabsf(acc * sc));
  }
}

// ---------------- mreduceA: stage-A partial reduce over c (in-place) ---------
// 20 u-chunks x 16 c-chunks = 320 blocks. Block (cc,uc) sums its NC/16 slices
// for 256 u-values and writes in-place to slice cc*chunk (within read set).
__global__ __launch_bounds__(256) void mreduceA_kernel(float* __restrict__ wsf,
                                                       int NC)
{
  const int uc = blockIdx.x % 20;
  const int cc = blockIdx.x / 20;                 // [0,16)
  const int u = uc * 256 + threadIdx.x;           // [0, 5120)
  float* base = wsf + PMOM_OFF + u;
  const int chunk = NC >> 4;                      // multiple of 8 (NC>=512)
  float* dst = base + (size_t)cc * chunk * PROW;
  const float* src = dst;
  float a0=0.f,a1=0.f,a2=0.f,a3=0.f,a4=0.f,a5=0.f,a6=0.f,a7=0.f;
  for (int i = 0; i < chunk; i += 8) {
    a0 += src[(size_t)(i+0)*PROW]; a1 += src[(size_t)(i+1)*PROW];
    a2 += src[(size_t)(i+2)*PROW]; a3 += src[(size_t)(i+3)*PROW];
    a4 += src[(size_t)(i+4)*PROW]; a5 += src[(size_t)(i+5)*PROW];
    a6 += src[(size_t)(i+6)*PROW]; a7 += src[(size_t)(i+7)*PROW];
  }
  dst[0] = ((a0+a1)+(a2+a3)) + ((a4+a5)+(a6+a7));
}

// ---------------- combine: stage-B reduce + p~/cert per n --------------------
__global__ __launch_bounds__(256) void combine_kernel(
    const float* __restrict__ W2, const float* __restrict__ b2,
    float* __restrict__ wsf, int NC)
{
  __shared__ float sS[160];
  __shared__ float shv[2];
  const int t = threadIdx.x;
  if (t < 64) {                                  // Sy / Sy_abs from ypart
    float a = wsf[8 + t], bb = wsf[72 + t];
    #pragma unroll
    for (int m = 1; m < 64; m <<= 1) {
      a  += __shfl_xor(a, m);
      bb += __shfl_xor(bb, m);
    }
    if (t == 0) { shv[0] = a; shv[1] = bb; }
  }
  if (t < 160) {                                 // stage-B: final S values
    const int u = blockIdx.x * 160 + t;          // block covers n in [8bi,8bi+8)
    const float* base = wsf + PMOM_OFF + u;
    const int chunk = NC >> 4;
    float s = 0.f;
    #pragma unroll
    for (int cc = 0; cc < 16; ++cc) s += base[(size_t)cc * chunk * PROW];
    sS[t] = s;
  }
  __syncthreads();
  const float Sy = shv[0], SyA = shv[1];
  const int h = t & 31, ng = t >> 5;
  const int n = blockIdx.x * 8 + ng;
  const int id = n * HID + h;
  const float* cws = wsf + 8192;
  float T = cws[id] * Sy;                        // c_0 * S_0 (S_0 = sum y)
  #pragma unroll
  for (int k = 1; k <= DDEG; ++k)
    T = fmaf(cws[k * 8192 + id], sS[ng * DDEG + k - 1], T);
  float acc = W2[id] * T;
  float e   = fabsf(W2[id]) * fmaf(3.0f, wsf[245760 + id], 3e-3f);
  #pragma unroll
  for (int m = 1; m < 32; m <<= 1) {             // reduce over h
    acc += __shfl_xor(acc, m);
    e   += __shfl_xor(e, m);
  }
  if (h == 0) {
    wsf[7424 + n] = ALPHA_BF - fmaf(b2[n], Sy, acc);   // p~
    wsf[7680 + n] = fmaf(e, SyA, 128.0f);              // cert (+fp slack)
  }
}

// ---------------- zflag: certified flag + zero-path output writer ------------
__global__ __launch_bounds__(256) void zflag_kernel(float* __restrict__ wsf,
                                                    float* __restrict__ out)
{
  const int t = threadIdx.x;
  float v = wsf[7424 + t] - wsf[7680 + t];
  int ok = (v >= 0.f) ? 1 : 0;                   // NaN -> 0
  __shared__ int smi[256];
  __shared__ int okk;
  smi[t] = ok;
  __syncthreads();
  for (int off = 128; off > 0; off >>= 1) {
    if (t < off) smi[t] = smi[t] & smi[t + off];
    __syncthreads();
  }
  if (t == 0) {
    float Xo = __uint_as_float(*reinterpret_cast<unsigned int*>(&wsf[1]));
    okk = (smi[0] && (Xo <= XFIX)) ? 1 : 0;
  }
  __syncthreads();
  if (blockIdx.x == 0 && t == 0) wsf[0] = okk ? 1.f : 0.f;  // flag for stubs
  if (!okk) return;
  int i = blockIdx.x * 256 + t;                  // 257 blocks = 65792
  if (i < BATCHN + NF) out[i] = 0.f;             // exact zeros
}

// ================= exact fallback path (flagA==0 only) =======================
__global__ __launch_bounds__(256, 2) void zty_kernel(
    const float* __restrict__ x, const float* __restrict__ y,
    const float* __restrict__ W1, const float* __restrict__ b1,
    const float* __restrict__ W2, const float* __restrict__ b2,
    const float* __restrict__ flag, float* __restrict__ part, int rows)
{
  if (flag[0] >= 0.5f) return;
  const int n = threadIdx.x;
  const int blk = blockIdx.x;
  float w1s[HID], b1s[HID], w2[HID];
  float base = b2[n];
  #pragma unroll
  for (int h = 0; h < HID; ++h) {
    w1s[h] = W1[n * HID + h] * K2C;
    b1s[h] = b1[n * HID + h] * K2C;
    w2[h]  = W2[n * HID + h];
    base  += w2[h];
  }
  const int b0 = blk * rows;
  const float* xp = x + (size_t)b0 * NF + n;
  float xv = xp[0];
  float yv = y[b0];
  float zty = 0.f;
  for (int r = 0; r < rows; ++r) {
    int rn = (r + 1 < rows) ? (r + 1) : r;
    float xnext = xp[(size_t)rn * NF];
    float ynext = y[b0 + rn];
    float a0 = 0.f, a1 = 0.f, a2 = 0.f, a3 = 0.f;
    #pragma unroll
    for (int h = 0; h < HID; h += 4) {
      float u0 = fmaf(xv, w1s[h + 0], b1s[h + 0]);
      float u1 = fmaf(xv, w1s[h + 1], b1s[h + 1]);
      float u2 = fmaf(xv, w1s[h + 2], b1s[h + 2]);
      float u3 = fmaf(xv, w1s[h + 3], b1s[h + 3]);
      float e0 = fexp2(u0), e1 = fexp2(u1), e2 = fexp2(u2), e3 = fexp2(u3);
      a0 = fmaf(w2[h + 0], frcp(e0 + 1.f), a0);
      a1 = fmaf(w2[h + 1], frcp(e1 + 1.f), a1);
      a2 = fmaf(w2[h + 2], frcp(e2 + 1.f), a2);
      a3 = fmaf(w2[h + 3], frcp(e3 + 1.f), a3);
    }
    float z = fmaf(-2.f, (a0 + a1) + (a2 + a3), base);
    zty = fmaf(z, yv, zty);
    xv = xnext; yv = ynext;
  }
  part[(size_t)blk * NF + n] = zty;
}

__global__ __launch_bounds__(256) void reduce1(const float* __restrict__ flag,
                                               const float* __restrict__ part,
                                               float* __restrict__ part2,
                                               int chunks)
{
  if (flag[0] >= 0.5f) return;
  int n = threadIdx.x, j = blockIdx.x;
  float s = 0.f;
  for (int k = 0; k < chunks; ++k) s += part[(size_t)(j * chunks + k) * NF + n];
  part2[(size_t)j * NF + n] = s;
}

// merged reduce2 + qinit
__global__ __launch_bounds__(256) void fbmid_kernel(const float* __restrict__ flag,
                                                    const float* __restrict__ part2,
                                                    float* __restrict__ p,
                                                    float* __restrict__ Q)
{
  if (flag[0] >= 0.5f) return;
  int idx = blockIdx.x * 256 + threadIdx.x;      // 256 blocks -> 65536
  int i = idx >> 8, j = idx & 255;
  Q[idx] = (i == j) ? JITTERF : 0.f;
  if (blockIdx.x == 0) {
    int n = threadIdx.x;
    float s = 0.f;
    for (int k = 0; k < 64; ++k) s += part2[(size_t)k * NF + n];
    p[n] = ALPHA_BF - s;
  }
}

__global__ __launch_bounds__(256) void qacc(
    const float* __restrict__ x,
    const float* __restrict__ W1, const float* __restrict__ b1,
    const float* __restrict__ W2, const float* __restrict__ b2,
    const float* __restrict__ flag, float* __restrict__ Q)
{
  if (flag[0] >= 0.5f) return;
  __shared__ float zsh[64 * NF];                 // 64 KiB
  const int t = threadIdx.x;
  float w1s[HID], b1s[HID], w2[HID];
  float base = b2[t];
  #pragma unroll
  for (int h = 0; h < HID; ++h) {
    w1s[h] = W1[t * HID + h] * K2C;
    b1s[h] = b1[t * HID + h] * K2C;
    w2[h]  = W2[t * HID + h];
    base  += w2[h];
  }
  const int b0 = blockIdx.x * 64;
  for (int r = 0; r < 64; ++r) {
    float xv = x[(size_t)(b0 + r) * NF + t];
    float acc = 0.f;
    #pragma unroll
    for (int h = 0; h < HID; ++h) {
      float u = fmaf(xv, w1s[h], b1s[h]);
      acc = fmaf(w2[h], frcp(fexp2(u) + 1.f), acc);
    }
    zsh[r * NF + t] = fmaf(-2.f, acc, base);
  }
  __syncthreads();
  for (int j = 0; j < NF; ++j) {
    float s = 0.f;
    for (int r = 0; r < 64; ++r) s += zsh[r * NF + t] * zsh[r * NF + j];
    atomicAdd(&Q[t * NF + j], s);
  }
}

__global__ __launch_bounds__(256) void solver_kernel(
    const float* __restrict__ flag, const float* __restrict__ p,
    const float* __restrict__ Q, float* __restrict__ L, float* __restrict__ Qe,
    float* __restrict__ lamg, float* __restrict__ dout_lam)
{
  if (flag[0] >= 0.5f) return;
  const int t = threadIdx.x;
  __shared__ float sm[NF];
  __shared__ float lam_s[NF];
  for (int i = 0; i < NF; ++i) L[i * NF + t] = (t <= i) ? Q[i * NF + t] : 0.f;
  __syncthreads();
  for (int k = 0; k < NF; ++k) {                 // right-looking Cholesky
    if (t == 0) L[k * NF + k] = sqrtf(L[k * NF + k]);
    __syncthreads();
    float lkk = L[k * NF + k];
    if (t > k) L[t * NF + k] /= lkk;
    __syncthreads();
    if (t > k) {
      float ltk = L[t * NF + k];
      for (int i = k + 1; i <= t; ++i) L[t * NF + i] -= ltk * L[i * NF + k];
    }
    __syncthreads();
  }
  for (int i = 0; i < NF; ++i) {                 // Qe = L L^T
    int m = (i < t) ? i : t;
    float s = 0.f;
    for (int k = 0; k <= m; ++k) s += L[i * NF + k] * L[t * NF + k];
    Qe[i * NF + t] = s;
  }
  __syncthreads();
  lam_s[t] = 1.f;
  __syncthreads();
  float lmax = 1.f;
  for (int it = 0; it < 256; ++it) {             // power iteration
    float s = 0.f;
    for (int k = 0; k < NF; ++k) s += Qe[t * NF + k] * lam_s[k];
    sm[t] = s * s;
    __syncthreads();
    for (int off = 128; off > 0; off >>= 1) {
      if (t < off) sm[t] += sm[t + off];
      __syncthreads();
    }
    float nrm = sqrtf(sm[0]);
    __syncthreads();
    lam_s[t] = s / nrm;
    lmax = nrm;
    __syncthreads();
  }
  float step = 1.0f / lmax;
  lam_s[t] = 0.f;
  __syncthreads();
  float pv = p[t];
  for (int it = 0; it < QP_ITERS_N; ++it) {
    float s = 0.f;
    for (int k = 0; k < NF; ++k) s += Qe[t * NF + k] * lam_s[k];
    float ln = fmaxf(lam_s[t] - step * (s + pv), 0.f);
    __syncthreads();
    lam_s[t] = ln;
    __syncthreads();
  }
  dout_lam[t] = lam_s[t];
  lamg[t] = lam_s[t];
}

__global__ __launch_bounds__(256) void yhat_kernel(
    const float* __restrict__ x,
    const float* __restrict__ W1, const float* __restrict__ b1,
    const float* __restrict__ W2, const float* __restrict__ b2,
    const float* __restrict__ flag, const float* __restrict__ lamg,
    float* __restrict__ yhat)
{
  if (flag[0] >= 0.5f) return;
  const int b = blockIdx.x * 256 + threadIdx.x;
  __shared__ float lam_s[NF];
  lam_s[threadIdx.x] = lamg[threadIdx.x];
  __syncthreads();
  float acc = 0.f;
  for (int n = 0; n < NF; ++n) {
    float xv = x[(size_t)b * NF + n];
    float zacc = 0.f, base = b2[n];
    for (int h = 0; h < HID; ++h) {
      float w2h = W2[n * HID + h];
      base += w2h;
      float u = fmaf(xv, W1[n * HID + h] * K2C, b1[n * HID + h] * K2C);
      zacc = fmaf(w2h, frcp(fexp2(u) + 1.f), zacc);
    }
    acc = fmaf(fmaf(-2.f, zacc, base), lam_s[n], acc);
  }
  yhat[b] = acc;
}

// ---------------- host launcher ---------------------------------------------
extern "C" void kernel_launch(void* const* d_in, const int* in_sizes, int n_in,
                              void* d_out, int out_size, void* d_ws, size_t ws_size,
                              hipStream_t stream) {
  const float* x  = (const float*)d_in[0];
  const float* y  = (const float*)d_in[1];
  const float* W1 = (const float*)d_in[2];
  const float* b1 = (const float*)d_in[3];
  const float* W2 = (const float*)d_in[4];
  const float* b2 = (const float*)d_in[5];
  float* out = (float*)d_out;            // [0,65536): y_hat ; [65536,65792): lam
  float* ws  = (float*)d_ws;

  // pmom footprint tier: NC=2048 needs 42MB+1MB header; tier down if no fit
  int NC = 2048;
  while (NC > 512 &&
         (PMOM_OFF + (size_t)NC * PROW) * 4 > ws_size) NC >>= 1;

  // fallback overlay inside pmom region (disjoint lifetime)
  const int nblk = 2048, rows_f = BATCHN / nblk, chunks = nblk / 64;
  float* flagA = ws;
  float* part  = ws + PMOM_OFF;
  float* part2 = part + (size_t)nblk * NF;
  float* p_ex  = part2 + 16384;
  float* lam   = p_ex + 256;
  float* Q     = lam + 256;
  float* L     = Q + 65536;
  float* Qe    = L + 65536;

  // fast certified path
  ysum_kernel<<<64, 256, 0, stream>>>(y, ws);
  momentcoeff_kernel<<<NC + 1408, 256, 0, stream>>>(x, y, W1, b1, ws, NC);
  mreduceA_kernel<<<320, 256, 0, stream>>>(ws, NC);
  combine_kernel<<<32, 256, 0, stream>>>(W2, b2, ws, NC);
  zflag_kernel<<<257, 256, 0, stream>>>(ws, out);

  // exact fallback (flag-guarded; near-free when certified)
  zty_kernel<<<nblk, 256, 0, stream>>>(x, y, W1, b1, W2, b2, flagA, part, rows_f);
  reduce1<<<64, 256, 0, stream>>>(flagA, part, part2, chunks);
  fbmid_kernel<<<256, 256, 0, stream>>>(flagA, part2, p_ex, Q);
  qacc<<<1024, 256, 0, stream>>>(x, W1, b1, W2, b2, flagA, Q);
  solver_kernel<<<1, 256, 0, stream>>>(flagA, p_ex, Q, L, Qe, lam, out + BATCHN);
  yhat_kernel<<<BATCHN / 256, 256, 0, stream>>>(x, W1, b1, W2, b2, flagA, lam, out);
}

// Round 10
// 131.325 us; speedup vs baseline: 1.0706x; 1.0706x over previous
//
#include <hip/hip_runtime.h>
#include <math.h>

// DifferentiableLassoSelector: B=65536, n=256, h=32.
// p = 6553.6 - Z^T y > 0 elementwise (~40 sigma margin) => projected-gradient
// QP stays at lam=0 exactly => y_hat = 0 exactly.
// Chebyshev factorization with h PRE-COMBINED: C_k[n] = sum_h W2 c_k[n,h],
// z~[b,n] = sum_k C_k T_k(x/X), zty[n] = sum_b y z~ accumulated in ONE register.
// r4-r9 post-mortem chain: global atomics (891us) -> latency-bound reduce ->
// 29-42MB of 80B-strided pmom scatters serialize at ~0.55 TB/s (duration
// scaled with WRITE_SIZE across r6/r7/r9; r1 with 1MB writes hit 71% VALU).
// This round removes the moment writes entirely: heavy kernel writes 2MB
// coalesced partials. Certification (observed coeff tail, deterministic
// unique-writer tailpart) gates the zero path; exact fallback is flag-guarded.

#define NF 256
#define HID 32
#define BATCHN 65536
#define ALPHA_BF 6553.6f               // ALPHA * BATCH
#define JITTERF 1e-4f
#define QP_ITERS_N 500
#define K2C 2.8853900817779268f        // 2*log2(e): exp2(K2C*u) = e^{2u}
#define XFIX 6.5f
#define INVX (1.0f / 6.5f)
#define NNODE 44                       // Chebyshev nodes; coeffs k=0..43
// ws float layout:
// 0: flagA | 1: Xobs bits | 8..72: ypart[64] | 72..136: yabspart[64]
// 256:     Carr[21][256]     -> 5632
// 5632:    tailpart[23][256] -> 11520   (k=21..43, unique writer per (k,n))
// 11520:   sw2[256]          -> 11776
// 12288:   part2[64][256]    -> 28672
// 28672:   part[2048][256]   -> 552960
// 552960:  fb_part[2048][256]-> 1077248
// 1077248: fb_part2[16384]   -> 1093632
// 1093632: p_ex[256]         -> 1093888
// 1093888: lam[256]          -> 1094144
// 1094144: Q | L | Qe        -> 1290752  (~5.2 MB total, ws proven >= 43 MB)

#if __has_builtin(__builtin_amdgcn_exp2f)
__device__ __forceinline__ float fexp2(float x) { return __builtin_amdgcn_exp2f(x); }
#else
__device__ __forceinline__ float fexp2(float x) { return exp2f(x); }
#endif
#if __has_builtin(__builtin_amdgcn_rcpf)
__device__ __forceinline__ float frcp(float x) { return __builtin_amdgcn_rcpf(x); }
#else
__device__ __forceinline__ float frcp(float x) { return 1.0f / x; }
#endif

// ---------------- mcoeff: ysum (blocks 0..63) + combined coeffs (64..1471) ---
__global__ __launch_bounds__(256) void mcoeff_kernel(
    const float* __restrict__ y,
    const float* __restrict__ W1, const float* __restrict__ b1,
    const float* __restrict__ W2, float* __restrict__ wsf)
{
  const int t = threadIdx.x;
  if ((int)blockIdx.x < 64) {
    // ---- ysum role: per-block partial sums of y and |y| ----
    const int gi = blockIdx.x * 256 + t;
    if (gi == 0) wsf[1] = 0.f;                  // Xobs (atomicMax target)
    float4 v = *reinterpret_cast<const float4*>(y + gi * 4);
    float s  = (v.x + v.y) + (v.z + v.w);
    float sa = (fabsf(v.x) + fabsf(v.y)) + (fabsf(v.z) + fabsf(v.w));
    #pragma unroll
    for (int m = 1; m < 64; m <<= 1) {
      s  += __shfl_xor(s, m);
      sa += __shfl_xor(sa, m);
    }
    __shared__ float ls[4], la[4];
    int w = t >> 6;
    if ((t & 63) == 0) { ls[w] = s; la[w] = sa; }
    __syncthreads();
    if (t == 0) {
      wsf[8  + blockIdx.x] = (ls[0] + ls[1]) + (ls[2] + ls[3]);
      wsf[72 + blockIdx.x] = (la[0] + la[1]) + (la[2] + la[3]);
    }
  } else {
    // ---- coeff role: thread = (id, k); h-reduced combined coefficients ----
    const int cb = blockIdx.x - 64;            // [0, 1408)
    const int k  = cb >> 5;                    // 0..43
    const int id = (cb & 31) * 256 + t;        // 0..8191 = n*32+h
    const int h  = t & 31;
    const int n  = id >> 5;
    const float aX  = W1[id] * XFIX;
    const float bb  = b1[id];
    const float w2v = W2[id];
    const float kf = (float)k;
    const float C1 = (float)(M_PI / (double)NNODE);
    float acc = 0.f;
    #pragma unroll 4
    for (int jn = 0; jn < NNODE; ++jn) {
      float ang = ((float)jn + 0.5f) * C1;
      float tj  = __cosf(ang);
      float u   = fmaf(aX, tj, bb);
      float f   = fmaf(-2.f, frcp(fexp2(K2C * u) + 1.f), 1.f);  // exact tanh
      acc = fmaf(f, __cosf(kf * ang), acc);
    }
    const float ck = acc * ((k == 0) ? (1.0f / (float)NNODE)
                                     : (2.0f / (float)NNODE));
    float comb = w2v * ck;                     // signed, for C_k[n]
    float cabs = fabsf(comb);                  // |W2 c_k|, for tail
    float wabs = fabsf(w2v);                   // |W2|, for k==0 slack
    #pragma unroll
    for (int m = 1; m < 32; m <<= 1) {         // reduce over h (32 lanes)
      comb += __shfl_xor(comb, m);
      cabs += __shfl_xor(cabs, m);
      wabs += __shfl_xor(wabs, m);
    }
    if (h == 0) {
      if (k <= 20) wsf[256 + k * 256 + n] = comb;
      else         wsf[5632 + (k - 21) * 256 + n] = cabs;
      if (k == 0)  wsf[11520 + n] = wabs;
    }
  }
}

// ---------------- zmom: heavy kernel, direct z~ accumulation -----------------
#define ZSTEP(C, ZA) { float Tn = fmaf(t2, Tc, -Tm); \
  ZA = fmaf(C, Tn, ZA); Tm = Tc; Tc = Tn; }
#define ZROW(XV, YV, ZT) { \
  mx = fmaxf(mx, fabsf(XV)); \
  float xh = (XV) * INVX; \
  float t2 = xh + xh; \
  float Tm = 1.f, Tc = xh; \
  float za = fmaf(c01, xh, c00); \
  float zb = 0.f; \
  ZSTEP(c02, zb) ZSTEP(c03, za) ZSTEP(c04, zb) ZSTEP(c05, za) \
  ZSTEP(c06, zb) ZSTEP(c07, za) ZSTEP(c08, zb) ZSTEP(c09, za) \
  ZSTEP(c10, zb) ZSTEP(c11, za) ZSTEP(c12, zb) ZSTEP(c13, za) \
  ZSTEP(c14, zb) ZSTEP(c15, za) ZSTEP(c16, zb) ZSTEP(c17, za) \
  ZSTEP(c18, zb) ZSTEP(c19, za) ZSTEP(c20, zb) \
  ZT = fmaf(za + zb, (YV), ZT); }

__global__ __launch_bounds__(256, 2) void zmom_kernel(
    const float* __restrict__ x, const float* __restrict__ y,
    float* __restrict__ wsf)
{
  const int n = threadIdx.x;
  const float* Carr = wsf + 256;
  const float c00 = Carr[n],            c01 = Carr[256 + n];
  const float c02 = Carr[512 + n],      c03 = Carr[768 + n];
  const float c04 = Carr[1024 + n],     c05 = Carr[1280 + n];
  const float c06 = Carr[1536 + n],     c07 = Carr[1792 + n];
  const float c08 = Carr[2048 + n],     c09 = Carr[2304 + n];
  const float c10 = Carr[2560 + n],     c11 = Carr[2816 + n];
  const float c12 = Carr[3072 + n],     c13 = Carr[3328 + n];
  const float c14 = Carr[3584 + n],     c15 = Carr[3840 + n];
  const float c16 = Carr[4096 + n],     c17 = Carr[4352 + n];
  const float c18 = Carr[4608 + n],     c19 = Carr[4864 + n];
  const float c20 = Carr[5120 + n];
  const int b0 = blockIdx.x * 32;                 // 2048 blocks x 32 rows
  const float* xp = x + (size_t)b0 * NF + n;
  const float2* yp2 = reinterpret_cast<const float2*>(y + b0);
  float zty0 = 0.f, zty1 = 0.f, mx = 0.f;
  // 2-row groups, prefetch depth 2, G = 16 groups
  float xa0 = xp[0],      xa1 = xp[NF];
  float2 ya = yp2[0];
  float xb0 = xp[2 * NF], xb1 = xp[3 * NF];
  float2 yb = yp2[1];
  const float* xq = xp + 4 * NF;
  for (int g = 0; g < 14; ++g) {
    float xn0 = xq[0], xn1 = xq[NF];
    float2 yn = yp2[g + 2];
    ZROW(xa0, ya.x, zty0)
    ZROW(xa1, ya.y, zty1)
    xa0 = xb0; xa1 = xb1; ya = yb;
    xb0 = xn0; xb1 = xn1; yb = yn;
    xq += 2 * NF;
  }
  ZROW(xa0, ya.x, zty0)
  ZROW(xa1, ya.y, zty1)
  ZROW(xb0, yb.x, zty0)
  ZROW(xb1, yb.y, zty1)
  #pragma unroll
  for (int m = 1; m < 64; m <<= 1) mx = fmaxf(mx, __shfl_xor(mx, m));
  if ((n & 63) == 0)
    atomicMax(reinterpret_cast<unsigned int*>(&wsf[1]), __float_as_uint(mx));
  wsf[28672 + (size_t)blockIdx.x * NF + n] = zty0 + zty1;   // coalesced 1KB/blk
}

// ---------------- red1f: part[2048][256] -> part2[64][256] -------------------
__global__ __launch_bounds__(256) void red1f_kernel(float* __restrict__ wsf)
{
  const int n = threadIdx.x, j = blockIdx.x;      // 64 blocks
  const float* p = wsf + 28672 + (size_t)j * 32 * NF + n;
  float s0 = 0.f, s1 = 0.f, s2 = 0.f, s3 = 0.f;
  #pragma unroll
  for (int k = 0; k < 32; k += 4) {
    s0 += p[(size_t)k * NF];       s1 += p[(size_t)(k + 1) * NF];
    s2 += p[(size_t)(k + 2) * NF]; s3 += p[(size_t)(k + 3) * NF];
  }
  wsf[12288 + (size_t)j * NF + n] = (s0 + s1) + (s2 + s3);
}

// ---------------- zwflag: redundant flag computation + zero-write ------------
__global__ __launch_bounds__(256) void zwflag_kernel(
    const float* __restrict__ b2, float* __restrict__ wsf,
    float* __restrict__ out)
{
  const int t = threadIdx.x;                      // t == feature n
  __shared__ float shv[2];
  if (t < 64) {
    float a = wsf[8 + t], bb = wsf[72 + t];
    #pragma unroll
    for (int m = 1; m < 64; m <<= 1) {
      a  += __shfl_xor(a, m);
      bb += __shfl_xor(bb, m);
    }
    if (t == 0) { shv[0] = a; shv[1] = bb; }
  }
  __syncthreads();
  const float Sy = shv[0], SyA = shv[1];
  float s = 0.f;
  #pragma unroll
  for (int j = 0; j < 64; ++j) s += wsf[12288 + j * NF + t];
  float tailn = 0.f;
  #pragma unroll
  for (int q = 0; q < 23; ++q) tailn += wsf[5632 + q * 256 + t];
  float ptil = ALPHA_BF - (s + b2[t] * Sy);
  float cert = fmaf(fmaf(3.0f, tailn, 3e-3f * wsf[11520 + t]), SyA, 128.0f);
  int ok = ((ptil - cert) >= 0.f) ? 1 : 0;        // NaN -> 0
  __shared__ int smi[256];
  __shared__ int okk;
  smi[t] = ok;
  __syncthreads();
  for (int off = 128; off > 0; off >>= 1) {
    if (t < off) smi[t] = smi[t] & smi[t + off];
    __syncthreads();
  }
  if (t == 0) {
    float Xo = __uint_as_float(*reinterpret_cast<unsigned int*>(&wsf[1]));
    okk = (smi[0] && (Xo <= XFIX)) ? 1 : 0;
    if (blockIdx.x == 0) wsf[0] = okk ? 1.f : 0.f;   // flag for fallback stubs
  }
  __syncthreads();
  if (!okk) return;
  int i = blockIdx.x * 256 + t;                   // 257 blocks = 65792 exactly
  if (i < BATCHN + NF) out[i] = 0.f;              // exact zeros
}

// ================= exact fallback path (flagA==0 only) =======================
__global__ __launch_bounds__(256, 2) void zty_kernel(
    const float* __restrict__ x, const float* __restrict__ y,
    const float* __restrict__ W1, const float* __restrict__ b1,
    const float* __restrict__ W2, const float* __restrict__ b2,
    const float* __restrict__ flag, float* __restrict__ part, int rows)
{
  if (flag[0] >= 0.5f) return;
  const int n = threadIdx.x;
  const int blk = blockIdx.x;
  float w1s[HID], b1s[HID], w2[HID];
  float base = b2[n];
  #pragma unroll
  for (int h = 0; h < HID; ++h) {
    w1s[h] = W1[n * HID + h] * K2C;
    b1s[h] = b1[n * HID + h] * K2C;
    w2[h]  = W2[n * HID + h];
    base  += w2[h];
  }
  const int b0 = blk * rows;
  const float* xp = x + (size_t)b0 * NF + n;
  float xv = xp[0];
  float yv = y[b0];
  float zty = 0.f;
  for (int r = 0; r < rows; ++r) {
    int rn = (r + 1 < rows) ? (r + 1) : r;
    float xnext = xp[(size_t)rn * NF];
    float ynext = y[b0 + rn];
    float a0 = 0.f, a1 = 0.f, a2 = 0.f, a3 = 0.f;
    #pragma unroll
    for (int h = 0; h < HID; h += 4) {
      float u0 = fmaf(xv, w1s[h + 0], b1s[h + 0]);
      float u1 = fmaf(xv, w1s[h + 1], b1s[h + 1]);
      float u2 = fmaf(xv, w1s[h + 2], b1s[h + 2]);
      float u3 = fmaf(xv, w1s[h + 3], b1s[h + 3]);
      float e0 = fexp2(u0), e1 = fexp2(u1), e2 = fexp2(u2), e3 = fexp2(u3);
      a0 = fmaf(w2[h + 0], frcp(e0 + 1.f), a0);
      a1 = fmaf(w2[h + 1], frcp(e1 + 1.f), a1);
      a2 = fmaf(w2[h + 2], frcp(e2 + 1.f), a2);
      a3 = fmaf(w2[h + 3], frcp(e3 + 1.f), a3);
    }
    float z = fmaf(-2.f, (a0 + a1) + (a2 + a3), base);
    zty = fmaf(z, yv, zty);
    xv = xnext; yv = ynext;
  }
  part[(size_t)blk * NF + n] = zty;
}

__global__ __launch_bounds__(256) void reduce1(const float* __restrict__ flag,
                                               const float* __restrict__ part,
                                               float* __restrict__ part2,
                                               int chunks)
{
  if (flag[0] >= 0.5f) return;
  int n = threadIdx.x, j = blockIdx.x;
  float s = 0.f;
  for (int k = 0; k < chunks; ++k) s += part[(size_t)(j * chunks + k) * NF + n];
  part2[(size_t)j * NF + n] = s;
}

// merged reduce2 + qinit
__global__ __launch_bounds__(256) void fbmid_kernel(const float* __restrict__ flag,
                                                    const float* __restrict__ part2,
                                                    float* __restrict__ p,
                                                    float* __restrict__ Q)
{
  if (flag[0] >= 0.5f) return;
  int idx = blockIdx.x * 256 + threadIdx.x;      // 256 blocks -> 65536
  int i = idx >> 8, j = idx & 255;
  Q[idx] = (i == j) ? JITTERF : 0.f;
  if (blockIdx.x == 0) {
    int n = threadIdx.x;
    float s = 0.f;
    for (int k = 0; k < 64; ++k) s += part2[(size_t)k * NF + n];
    p[n] = ALPHA_BF - s;
  }
}

__global__ __launch_bounds__(256) void qacc(
    const float* __restrict__ x,
    const float* __restrict__ W1, const float* __restrict__ b1,
    const float* __restrict__ W2, const float* __restrict__ b2,
    const float* __restrict__ flag, float* __restrict__ Q)
{
  if (flag[0] >= 0.5f) return;
  __shared__ float zsh[64 * NF];                 // 64 KiB
  const int t = threadIdx.x;
  float w1s[HID], b1s[HID], w2[HID];
  float base = b2[t];
  #pragma unroll
  for (int h = 0; h < HID; ++h) {
    w1s[h] = W1[t * HID + h] * K2C;
    b1s[h] = b1[t * HID + h] * K2C;
    w2[h]  = W2[t * HID + h];
    base  += w2[h];
  }
  const int b0 = blockIdx.x * 64;
  for (int r = 0; r < 64; ++r) {
    float xv = x[(size_t)(b0 + r) * NF + t];
    float acc = 0.f;
    #pragma unroll
    for (int h = 0; h < HID; ++h) {
      float u = fmaf(xv, w1s[h], b1s[h]);
      acc = fmaf(w2[h], frcp(fexp2(u) + 1.f), acc);
    }
    zsh[r * NF + t] = fmaf(-2.f, acc, base);
  }
  __syncthreads();
  for (int j = 0; j < NF; ++j) {
    float s = 0.f;
    for (int r = 0; r < 64; ++r) s += zsh[r * NF + t] * zsh[r * NF + j];
    atomicAdd(&Q[t * NF + j], s);
  }
}

__global__ __launch_bounds__(256) void solver_kernel(
    const float* __restrict__ flag, const float* __restrict__ p,
    const float* __restrict__ Q, float* __restrict__ L, float* __restrict__ Qe,
    float* __restrict__ lamg, float* __restrict__ dout_lam)
{
  if (flag[0] >= 0.5f) return;
  const int t = threadIdx.x;
  __shared__ float sm[NF];
  __shared__ float lam_s[NF];
  for (int i = 0; i < NF; ++i) L[i * NF + t] = (t <= i) ? Q[i * NF + t] : 0.f;
  __syncthreads();
  for (int k = 0; k < NF; ++k) {                 // right-looking Cholesky
    if (t == 0) L[k * NF + k] = sqrtf(L[k * NF + k]);
    __syncthreads();
    float lkk = L[k * NF + k];
    if (t > k) L[t * NF + k] /= lkk;
    __syncthreads();
    if (t > k) {
      float ltk = L[t * NF + k];
      for (int i = k + 1; i <= t; ++i) L[t * NF + i] -= ltk * L[i * NF + k];
    }
    __syncthreads();
  }
  for (int i = 0; i < NF; ++i) {                 // Qe = L L^T
    int m = (i < t) ? i : t;
    float s = 0.f;
    for (int k = 0; k <= m; ++k) s += L[i * NF + k] * L[t * NF + k];
    Qe[i * NF + t] = s;
  }
  __syncthreads();
  lam_s[t] = 1.f;
  __syncthreads();
  float lmax = 1.f;
  for (int it = 0; it < 256; ++it) {             // power iteration
    float s = 0.f;
    for (int k = 0; k < NF; ++k) s += Qe[t * NF + k] * lam_s[k];
    sm[t] = s * s;
    __syncthreads();
    for (int off = 128; off > 0; off >>= 1) {
      if (t < off) sm[t] += sm[t + off];
      __syncthreads();
    }
    float nrm = sqrtf(sm[0]);
    __syncthreads();
    lam_s[t] = s / nrm;
    lmax = nrm;
    __syncthreads();
  }
  float step = 1.0f / lmax;
  lam_s[t] = 0.f;
  __syncthreads();
  float pv = p[t];
  for (int it = 0; it < QP_ITERS_N; ++it) {
    float s = 0.f;
    for (int k = 0; k < NF; ++k) s += Qe[t * NF + k] * lam_s[k];
    float ln = fmaxf(lam_s[t] - step * (s + pv), 0.f);
    __syncthreads();
    lam_s[t] = ln;
    __syncthreads();
  }
  dout_lam[t] = lam_s[t];
  lamg[t] = lam_s[t];
}

__global__ __launch_bounds__(256) void yhat_kernel(
    const float* __restrict__ x,
    const float* __restrict__ W1, const float* __restrict__ b1,
    const float* __restrict__ W2, const float* __restrict__ b2,
    const float* __restrict__ flag, const float* __restrict__ lamg,
    float* __restrict__ yhat)
{
  if (flag[0] >= 0.5f) return;
  const int b = blockIdx.x * 256 + threadIdx.x;
  __shared__ float lam_s[NF];
  lam_s[threadIdx.x] = lamg[threadIdx.x];
  __syncthreads();
  float acc = 0.f;
  for (int n = 0; n < NF; ++n) {
    float xv = x[(size_t)b * NF + n];
    float zacc = 0.f, base = b2[n];
    for (int h = 0; h < HID; ++h) {
      float w2h = W2[n * HID + h];
      base += w2h;
      float u = fmaf(xv, W1[n * HID + h] * K2C, b1[n * HID + h] * K2C);
      zacc = fmaf(w2h, frcp(fexp2(u) + 1.f), zacc);
    }
    acc = fmaf(fmaf(-2.f, zacc, base), lam_s[n], acc);
  }
  yhat[b] = acc;
}

// ---------------- host launcher ---------------------------------------------
extern "C" void kernel_launch(void* const* d_in, const int* in_sizes, int n_in,
                              void* d_out, int out_size, void* d_ws, size_t ws_size,
                              hipStream_t stream) {
  const float* x  = (const float*)d_in[0];
  const float* y  = (const float*)d_in[1];
  const float* W1 = (const float*)d_in[2];
  const float* b1 = (const float*)d_in[3];
  const float* W2 = (const float*)d_in[4];
  const float* b2 = (const float*)d_in[5];
  float* out = (float*)d_out;            // [0,65536): y_hat ; [65536,65792): lam
  float* ws  = (float*)d_ws;

  float* flagA    = ws;
  float* fb_part  = ws + 552960;
  float* fb_part2 = ws + 1077248;
  float* p_ex     = ws + 1093632;
  float* lam      = ws + 1093888;
  float* Q        = ws + 1094144;
  float* L        = Q + 65536;
  float* Qe       = L + 65536;

  // fast certified path (4 dispatches)
  mcoeff_kernel<<<1472, 256, 0, stream>>>(y, W1, b1, W2, ws);
  zmom_kernel<<<2048, 256, 0, stream>>>(x, y, ws);
  red1f_kernel<<<64, 256, 0, stream>>>(ws);
  zwflag_kernel<<<257, 256, 0, stream>>>(b2, ws, out);

  // exact fallback (flag-guarded; near-free when certified)
  zty_kernel<<<2048, 256, 0, stream>>>(x, y, W1, b1, W2, b2, flagA, fb_part, 32);
  reduce1<<<64, 256, 0, stream>>>(flagA, fb_part, fb_part2, 32);
  fbmid_kernel<<<256, 256, 0, stream>>>(flagA, fb_part2, p_ex, Q);
  qacc<<<1024, 256, 0, stream>>>(x, W1, b1, W2, b2, flagA, Q);
  solver_kernel<<<1, 256, 0, stream>>>(flagA, p_ex, Q, L, Qe, lam, out + BATCHN);
  yhat_kernel<<<BATCHN / 256, 256, 0, stream>>>(x, W1, b1, W2, b2, flagA, lam, out);
}